// Round 20
// baseline (179.219 us; speedup 1.0000x reference)
//
#include <hip/hip_runtime.h>
#include <hip/hip_bf16.h>
#include <stdint.h>

// Problem sizes (fixed)
#define MROWS 4096   // batch B
#define LFULL 4096   // L
#define NHALF 2048   // N = L/2
#define HDIM  2048   // H

typedef __bf16 bf16x8 __attribute__((ext_vector_type(8)));
typedef float  f32x4  __attribute__((ext_vector_type(4)));
typedef unsigned short u16x8 __attribute__((ext_vector_type(8)));

template<int V> struct ICt { static constexpr int value = V; };

__device__ __forceinline__ unsigned short f2bf(float f) {
    __hip_bfloat16 h = __float2bfloat16(f);
    return __builtin_bit_cast(unsigned short, h);
}
__device__ __forceinline__ float bf2f(unsigned short u) {
    return __builtin_bit_cast(float, (uint32_t)u << 16);
}
__device__ __forceinline__ float fast_tanh(float x) {
    float ax = fabsf(x);
    float e  = __expf(-2.0f * ax);
    float t  = (1.0f - e) / (1.0f + e);
    return copysignf(t, x);
}

__device__ __forceinline__ void gload_lds16(const void* g, void* l) {
    __builtin_amdgcn_global_load_lds(
        (const __attribute__((address_space(1))) uint32_t*)g,
        (__attribute__((address_space(3))) uint32_t*)l,
        16, 0, 0);
}

// ---------------------------------------------------------------------------
// Fused front-end (R15): cast x + 3 weight transposes in one launch.
// PERM (for W3): lane holds TWO CONSECUTIVE j; frag0=s_{j0},frag1=s_{j0+1},
// frag2=t_{j0},frag3=t_{j0+1}, j0 = bn*128+wn*32+2*l15 -> float4 tail access.
// dstrow = (j>>7)*256 + ((j>>5)&3)*64 + ((j&1)+2*half)*16 + ((j&31)>>1)
// ---------------------------------------------------------------------------
__device__ __forceinline__ void transpose_body(
    const float* __restrict__ W, __hip_bfloat16* __restrict__ WT,
    int K, int N, int bx, int by, bool perm,
    unsigned short (*lds)[66], int t)
{
    const int k0 = by * 64;
    const int n0 = bx * 64;

    #pragma unroll
    for (int it = 0; it < 4; ++it) {
        int kl = it * 16 + (t >> 4);
        int nl = (t & 15) * 4;
        float4 v = *(const float4*)(W + (size_t)(k0 + kl) * N + n0 + nl);
        lds[kl][nl + 0] = f2bf(v.x);
        lds[kl][nl + 1] = f2bf(v.y);
        lds[kl][nl + 2] = f2bf(v.z);
        lds[kl][nl + 3] = f2bf(v.w);
    }
    __syncthreads();

    int nl = t >> 2;
    int kc = (t & 3) * 16;
    unsigned short tmp[16];
    #pragma unroll
    for (int j = 0; j < 16; ++j) tmp[j] = lds[kc + j][nl];
    int jc = n0 + nl;
    int dstrow;
    if (perm) {
        int half = jc >> 11;          // 0 = s-col, 1 = t-col
        int j    = jc & 2047;
        dstrow = (j >> 7) * 256 + ((j >> 5) & 3) * 64
               + ((j & 1) + 2 * half) * 16 + ((j & 31) >> 1);
    } else {
        dstrow = jc;
    }
    u16x8* dst = (u16x8*)(WT + (size_t)dstrow * K + k0 + kc);
    dst[0] = *(u16x8*)&tmp[0];
    dst[1] = *(u16x8*)&tmp[8];
}

__global__ __launch_bounds__(256)
void prep_kernel(const float* __restrict__ x, __hip_bfloat16* __restrict__ xm,
                 float* __restrict__ ld,
                 const float* __restrict__ W1, __hip_bfloat16* __restrict__ W1T,
                 const float* __restrict__ W2, __hip_bfloat16* __restrict__ W2T,
                 const float* __restrict__ W3, __hip_bfloat16* __restrict__ W3T)
{
    __shared__ unsigned short lds[64][66];
    const int bid = blockIdx.x;
    const int t   = threadIdx.x;

    if (bid < 4096) {
        if (t == 0) ld[bid] = 0.0f;
        const size_t r = bid;
        const float4* xp = (const float4*)(x + r * LFULL + (size_t)t * 16);
        float4 a = xp[0], b = xp[1], d = xp[2], e = xp[3];
        u16x8 v;
        v[0] = f2bf(a.x); v[1] = f2bf(a.z);
        v[2] = f2bf(b.x); v[3] = f2bf(b.z);
        v[4] = f2bf(d.x); v[5] = f2bf(d.z);
        v[6] = f2bf(e.x); v[7] = f2bf(e.z);
        *(u16x8*)(xm + r * NHALF + (size_t)t * 8) = v;
    } else if (bid < 5120) {
        int b = bid - 4096;
        transpose_body(W1, W1T, HDIM, HDIM, b & 31, b >> 5, false, lds, t);
    } else if (bid < 6144) {
        int b = bid - 5120;
        transpose_body(W2, W2T, HDIM, HDIM, b & 31, b >> 5, false, lds, t);
    } else {
        int b = bid - 6144;
        transpose_body(W3, W3T, HDIM, LFULL, b & 63, b >> 6, true, lds, t);
    }
}

// ---------------------------------------------------------------------------
// 8-phase GEMM, counted-wait pipelined, minimal barriers (2 per K-tile).
// BMAJOR (G1/G2): consecutive wg share the B-panel (bn = wg/NBM) so each
// XCD's 32 contiguous blocks keep ONE 1 MB W-panel L2-resident and stream A
// from L3 (vs thrashing the full 8 MB W through a 4 MB L2).
// FUSED (GEMM3): consecutive-j s/t pairing in-register (frag0/1=s, frag2/3=t
// via PERM), coalesced float4 x-read / y-write, log_det atomics.
// ---------------------------------------------------------------------------
template<int BM, int BN, int KD, int NOUT, bool RELU, bool FUSED, bool BMAJOR>
__global__ __launch_bounds__(512)
void gemm8p(const __hip_bfloat16* __restrict__ A,
            const __hip_bfloat16* __restrict__ BT,
            const float* __restrict__ bias,
            __hip_bfloat16* __restrict__ C,
            const float* __restrict__ xg,
            float* __restrict__ yg,
            float* __restrict__ ldg)
{
    constexpr int MF = BM / 32, NF = BN / 64, MH = MF / 2, NH = NF / 2;
    constexpr int LA = BM / 128, LB = BN / 128;
    constexpr int NT = KD / 64;
    constexpr int ABYTES = BM * 128, BBYTES = BN * 128;
    constexpr int BBASE = 2 * ABYTES;
    __shared__ __align__(1024) char lds[2 * ABYTES + 2 * BBYTES];

    const int tid  = threadIdx.x;
    const int wave = tid >> 6, lane = tid & 63;
    const int wm = wave >> 2, wn = wave & 3;
    const int l15 = lane & 15, lhi = lane >> 4;

    // XCD-aware bijective swizzle (grid multiple of 8)
    const int nwg = gridDim.x;
    const int bid = blockIdx.x;
    const int wg  = (bid & 7) * (nwg >> 3) + (bid >> 3);
    constexpr int NBN = NOUT / BN;
    constexpr int NBM = MROWS / BM;
    int bm, bn;
    if (BMAJOR) { bm = wg % NBM; bn = wg / NBM; }
    else        { bm = wg / NBN; bn = wg % NBN; }

    const __hip_bfloat16* gA = A  + (size_t)(bm * BM) * KD;
    const __hip_bfloat16* gB = BT + (size_t)(bn * BN) * KD;

    // staging: row=tid>>3, 16B chunk=tid&7; source chunk XOR-swizzled by row&7
    const int srow = tid >> 3;
    const int scol = ((tid & 7) ^ (srow & 7)) * 8;   // elements
    char* sd = lds + srow * 128 + (tid & 7) * 16;    // linear LDS dest

    const __hip_bfloat16* pA = gA + (size_t)srow * KD + scol;
    const __hip_bfloat16* pB = gB + (size_t)srow * KD + scol;

    // ---- prologue: B(0)->Bbuf0, A(0)->Abuf0, B(1)->Bbuf1
    #pragma unroll
    for (int s = 0; s < LB; ++s) gload_lds16(pB + (size_t)(s * 64) * KD,             sd + BBASE + s * 8192);
    #pragma unroll
    for (int s = 0; s < LB; ++s) gload_lds16(pB + (size_t)(BN/2 + s * 64) * KD,      sd + BBASE + (BN/2) * 128 + s * 8192);
    #pragma unroll
    for (int s = 0; s < LA; ++s) gload_lds16(pA + (size_t)(s * 64) * KD,             sd + s * 8192);
    #pragma unroll
    for (int s = 0; s < LA; ++s) gload_lds16(pA + (size_t)(BM/2 + s * 64) * KD,      sd + (BM/2) * 128 + s * 8192);
    #pragma unroll
    for (int s = 0; s < LB; ++s) gload_lds16(pB + 64 + (size_t)(s * 64) * KD,        sd + BBASE + BBYTES + s * 8192);
    #pragma unroll
    for (int s = 0; s < LB; ++s) gload_lds16(pB + 64 + (size_t)(BN/2 + s * 64) * KD, sd + BBASE + BBYTES + (BN/2) * 128 + s * 8192);
    pA += 64; pB += 128;
    asm volatile("s_waitcnt vmcnt(4)" ::: "memory");
    __builtin_amdgcn_s_barrier();

    // ---- invariant per-lane LDS read bases (swizzle folds to (l15&7)<<4)
    const int arow0 = wm * (BM / 2) + l15;
    const int brow0 = wn * (BN / 4) + l15;
    const int swz   = (l15 & 7) << 4;
    const int colX[2] = { (lhi * 16) ^ swz, (64 + lhi * 16) ^ swz };
    const char* rA = lds + arow0 * 128;
    const char* rB = lds + brow0 * 128;

    bf16x8 af[MH][2], bf0[NH][2], bf1[NH][2];
    f32x4 acc[MF][NF] = {};

    // pre-read aLO(0), bLO(0)
    #pragma unroll
    for (int m = 0; m < MH; ++m)
        #pragma unroll
        for (int kk = 0; kk < 2; ++kk)
            af[m][kk] = *(const bf16x8*)(rA + colX[kk] + m * 2048);
    #pragma unroll
    for (int n = 0; n < NH; ++n)
        #pragma unroll
        for (int kk = 0; kk < 2; ++kk)
            bf0[n][kk] = *(const bf16x8*)(rB + colX[kk] + (BBASE + n * 2048));

    auto body = [&](int t, auto bufc) {
        constexpr int BUF   = decltype(bufc)::value;
        constexpr int ABUF  = BUF * ABYTES;
        constexpr int ABUFo = (BUF ^ 1) * ABYTES;
        constexpr int BBUF  = BBASE + BUF * BBYTES;
        constexpr int BBUFo = BBASE + (BUF ^ 1) * BBYTES;

        // ---- P0: stage A0(t+1); MFMA q00; read bHI(t)   [no barrier]
        if (t + 1 < NT) {
            #pragma unroll
            for (int s = 0; s < LA; ++s)
                gload_lds16(pA + (size_t)(s * 64) * KD, sd + ABUFo + s * 8192);
        }
        __builtin_amdgcn_s_setprio(1);
        #pragma unroll
        for (int kk = 0; kk < 2; ++kk)
            #pragma unroll
            for (int m = 0; m < MH; ++m)
                #pragma unroll
                for (int n = 0; n < NH; ++n)
                    acc[m][n] = __builtin_amdgcn_mfma_f32_16x16x32_bf16(af[m][kk], bf0[n][kk], acc[m][n], 0, 0, 0);
        __builtin_amdgcn_s_setprio(0);
        #pragma unroll
        for (int n = 0; n < NH; ++n)
            #pragma unroll
            for (int kk = 0; kk < 2; ++kk)
                bf1[n][kk] = *(const bf16x8*)(rB + colX[kk] + (BBUF + (NH + n) * 2048));

        // ---- P1: stage A1(t+1); MFMA q01; read aHI(t); BARRIER
        if (t + 1 < NT) {
            #pragma unroll
            for (int s = 0; s < LA; ++s)
                gload_lds16(pA + (size_t)(BM/2 + s * 64) * KD, sd + ABUFo + (BM/2) * 128 + s * 8192);
        }
        __builtin_amdgcn_s_setprio(1);
        #pragma unroll
        for (int kk = 0; kk < 2; ++kk)
            #pragma unroll
            for (int m = 0; m < MH; ++m)
                #pragma unroll
                for (int n = 0; n < NH; ++n)
                    acc[m][NH + n] = __builtin_amdgcn_mfma_f32_16x16x32_bf16(af[m][kk], bf1[n][kk], acc[m][NH + n], 0, 0, 0);
        __builtin_amdgcn_s_setprio(0);
        #pragma unroll
        for (int m = 0; m < MH; ++m)
            #pragma unroll
            for (int kk = 0; kk < 2; ++kk)
                af[m][kk] = *(const bf16x8*)(rA + colX[kk] + (ABUF + (MH + m) * 2048));
        __builtin_amdgcn_s_barrier();

        // ---- P2: stage B0(t+2); MFMA q10   [no barrier]
        if (t + 2 < NT) {
            #pragma unroll
            for (int s = 0; s < LB; ++s)
                gload_lds16(pB + (size_t)(s * 64) * KD, sd + BBUF + s * 8192);
        }
        __builtin_amdgcn_s_setprio(1);
        #pragma unroll
        for (int kk = 0; kk < 2; ++kk)
            #pragma unroll
            for (int m = 0; m < MH; ++m)
                #pragma unroll
                for (int n = 0; n < NH; ++n)
                    acc[MH + m][n] = __builtin_amdgcn_mfma_f32_16x16x32_bf16(af[m][kk], bf0[n][kk], acc[MH + m][n], 0, 0, 0);
        __builtin_amdgcn_s_setprio(0);

        // ---- P3: stage B1(t+2); vmcnt; BARRIER;
        //          read bLO(t+1); MFMA q11; read aLO(t+1)
        if (t + 2 < NT) {
            #pragma unroll
            for (int s = 0; s < LB; ++s)
                gload_lds16(pB + (size_t)(BN/2 + s * 64) * KD, sd + BBUF + (BN/2) * 128 + s * 8192);
            asm volatile("s_waitcnt vmcnt(4)" ::: "memory");
        } else {
            asm volatile("s_waitcnt vmcnt(0)" ::: "memory");
        }
        __builtin_amdgcn_s_barrier();
        if (t + 1 < NT) {
            #pragma unroll
            for (int n = 0; n < NH; ++n)
                #pragma unroll
                for (int kk = 0; kk < 2; ++kk)
                    bf0[n][kk] = *(const bf16x8*)(rB + colX[kk] + (BBUFo + n * 2048));
        }
        __builtin_amdgcn_s_setprio(1);
        #pragma unroll
        for (int kk = 0; kk < 2; ++kk)
            #pragma unroll
            for (int m = 0; m < MH; ++m)
                #pragma unroll
                for (int n = 0; n < NH; ++n)
                    acc[MH + m][NH + n] = __builtin_amdgcn_mfma_f32_16x16x32_bf16(af[m][kk], bf1[n][kk], acc[MH + m][NH + n], 0, 0, 0);
        __builtin_amdgcn_s_setprio(0);
        if (t + 1 < NT) {
            #pragma unroll
            for (int m = 0; m < MH; ++m)
                #pragma unroll
                for (int kk = 0; kk < 2; ++kk)
                    af[m][kk] = *(const bf16x8*)(rA + colX[kk] + (ABUFo + m * 2048));
        }
        pA += 64; pB += 64;
    };

    for (int tt = 0; tt < NT; tt += 2) {
        body(tt,     ICt<0>{});
        body(tt + 1, ICt<1>{});
    }

    const int crow0 = bm * BM + wm * (BM / 2) + lhi * 4;
    if constexpr (FUSED) {
        // PERM pairing: frag0=s_{j0}, frag1=s_{j0+1}, frag2=t_{j0},
        // frag3=t_{j0+1}, j0 = bn*128 + wn*32 + 2*l15 (even).
        // x/y access: one float4 at col 2*j0 (coalesced across l15).
        const int j0 = bn * (BN / 2) + wn * 32 + 2 * l15;
        const float2 sbv = *(const float2*)(bias + j0);
        const float2 tbv = *(const float2*)(bias + NHALF + j0);
        #pragma unroll
        for (int m = 0; m < MF; ++m) {
            #pragma unroll
            for (int r = 0; r < 4; ++r) {
                const int row = crow0 + m * 16 + r;
                float s0 = acc[m][0][r] + sbv.x;
                float s1 = acc[m][1][r] + sbv.y;
                float t0 = acc[m][2][r] + tbv.x;
                float t1 = acc[m][3][r] + tbv.y;
                float a0 = 2.0f * fast_tanh(s0);
                float a1 = 2.0f * fast_tanh(s1);
                float4 xv = *(const float4*)(xg + (size_t)row * LFULL + 2 * j0);
                float4 yv;
                yv.x = xv.x;                       // even col: exact copy
                yv.y = xv.y * __expf(a0) + t0;     // odd col: affine update
                yv.z = xv.z;
                yv.w = xv.w * __expf(a1) + t1;
                *(float4*)(yg + (size_t)row * LFULL + 2 * j0) = yv;
                float ldp = a0 + a1;
                ldp += __shfl_xor(ldp, 1, 64);
                ldp += __shfl_xor(ldp, 2, 64);
                ldp += __shfl_xor(ldp, 4, 64);
                ldp += __shfl_xor(ldp, 8, 64);
                if (l15 == 0) atomicAdd(&ldg[row], ldp);
            }
        }
    } else {
        // ---- C write: col = lane&15 (+n*16), row = lhi*4 + r (+m*16)
        const int ccol0 = bn * BN + wn * (BN / 4) + l15;
        #pragma unroll
        for (int m = 0; m < MF; ++m) {
            #pragma unroll
            for (int n = 0; n < NF; ++n) {
                int col = ccol0 + n * 16;
                float bv = bias[col];
                #pragma unroll
                for (int r = 0; r < 4; ++r) {
                    int row = crow0 + m * 16 + r;
                    float v = acc[m][n][r] + bv;
                    if (RELU) v = (v > 0.0f) ? v : 0.2f * v;
                    C[(size_t)row * NOUT + col] = __float2bfloat16(v);
                }
            }
        }
    }
}

// ---------------------------------------------------------------------------
extern "C" void kernel_launch(void* const* d_in, const int* in_sizes, int n_in,
                              void* d_out, int out_size, void* d_ws, size_t ws_size,
                              hipStream_t stream)
{
    const float* x  = (const float*)d_in[0];
    const float* W1 = (const float*)d_in[1];
    const float* b1 = (const float*)d_in[2];
    const float* W2 = (const float*)d_in[3];
    const float* b2 = (const float*)d_in[4];
    const float* W3 = (const float*)d_in[5];
    const float* b3 = (const float*)d_in[6];

    char* ws = (char*)d_ws;
    const size_t MB = 1u << 20;
    __hip_bfloat16* W3T  = (__hip_bfloat16*)(ws);              // 16 MB: 4096x2048 (PERM)
    __hip_bfloat16* h2   = (__hip_bfloat16*)(ws + 16 * MB);    // 16 MB: 4096x2048
    __hip_bfloat16* xmb  = (__hip_bfloat16*)(ws + 32 * MB);    // 16 MB
    __hip_bfloat16* W1T  = (__hip_bfloat16*)(ws + 48 * MB);    //  8 MB
    __hip_bfloat16* W2T  = (__hip_bfloat16*)(ws + 56 * MB);    //  8 MB
    __hip_bfloat16* h1   = (__hip_bfloat16*)(ws + 64 * MB);    // 16 MB

    float* y  = (float*)d_out;
    float* ld = y + (size_t)MROWS * LFULL;

    prep_kernel<<<8192, 256, 0, stream>>>(x, xmb, ld, W1, W1T, W2, W2T, W3, W3T);

    gemm8p<128, 256, 2048, 2048, true,  false, true ><<<dim3(256), dim3(512), 0, stream>>>(xmb, W1T, b1, h1, nullptr, nullptr, nullptr);
    gemm8p<128, 256, 2048, 2048, true,  false, true ><<<dim3(256), dim3(512), 0, stream>>>(h1,  W2T, b2, h2, nullptr, nullptr, nullptr);
    gemm8p<256, 256, 2048, 4096, false, true,  false><<<dim3(256), dim3(512), 0, stream>>>(h2,  W3T, b3, nullptr, x, y, ld);
}

// Round 21
// 176.350 us; speedup vs baseline: 1.0163x; 1.0163x over previous
//
#include <hip/hip_runtime.h>
#include <hip/hip_bf16.h>
#include <stdint.h>

// Problem sizes (fixed)
#define MROWS 4096   // batch B
#define LFULL 4096   // L
#define NHALF 2048   // N = L/2
#define HDIM  2048   // H

typedef __bf16 bf16x8 __attribute__((ext_vector_type(8)));
typedef float  f32x4  __attribute__((ext_vector_type(4)));
typedef unsigned short u16x8 __attribute__((ext_vector_type(8)));

template<int V> struct ICt { static constexpr int value = V; };

__device__ __forceinline__ unsigned short f2bf(float f) {
    __hip_bfloat16 h = __float2bfloat16(f);
    return __builtin_bit_cast(unsigned short, h);
}
__device__ __forceinline__ float bf2f(unsigned short u) {
    return __builtin_bit_cast(float, (uint32_t)u << 16);
}
__device__ __forceinline__ float fast_tanh(float x) {
    float ax = fabsf(x);
    float e  = __expf(-2.0f * ax);
    float t  = (1.0f - e) / (1.0f + e);
    return copysignf(t, x);
}

__device__ __forceinline__ void gload_lds16(const void* g, void* l) {
    __builtin_amdgcn_global_load_lds(
        (const __attribute__((address_space(1))) uint32_t*)g,
        (__attribute__((address_space(3))) uint32_t*)l,
        16, 0, 0);
}

// ---------------------------------------------------------------------------
// Fused front-end (R15): cast x + 3 weight transposes in one launch.
// PERM (for W3): lane holds TWO CONSECUTIVE j; frag0=s_{j0},frag1=s_{j0+1},
// frag2=t_{j0},frag3=t_{j0+1}, j0 = bn*128+wn*32+2*l15 -> float4 tail access.
// dstrow = (j>>7)*256 + ((j>>5)&3)*64 + ((j&1)+2*half)*16 + ((j&31)>>1)
// ---------------------------------------------------------------------------
__device__ __forceinline__ void transpose_body(
    const float* __restrict__ W, __hip_bfloat16* __restrict__ WT,
    int K, int N, int bx, int by, bool perm,
    unsigned short (*lds)[66], int t)
{
    const int k0 = by * 64;
    const int n0 = bx * 64;

    #pragma unroll
    for (int it = 0; it < 4; ++it) {
        int kl = it * 16 + (t >> 4);
        int nl = (t & 15) * 4;
        float4 v = *(const float4*)(W + (size_t)(k0 + kl) * N + n0 + nl);
        lds[kl][nl + 0] = f2bf(v.x);
        lds[kl][nl + 1] = f2bf(v.y);
        lds[kl][nl + 2] = f2bf(v.z);
        lds[kl][nl + 3] = f2bf(v.w);
    }
    __syncthreads();

    int nl = t >> 2;
    int kc = (t & 3) * 16;
    unsigned short tmp[16];
    #pragma unroll
    for (int j = 0; j < 16; ++j) tmp[j] = lds[kc + j][nl];
    int jc = n0 + nl;
    int dstrow;
    if (perm) {
        int half = jc >> 11;          // 0 = s-col, 1 = t-col
        int j    = jc & 2047;
        dstrow = (j >> 7) * 256 + ((j >> 5) & 3) * 64
               + ((j & 1) + 2 * half) * 16 + ((j & 31) >> 1);
    } else {
        dstrow = jc;
    }
    u16x8* dst = (u16x8*)(WT + (size_t)dstrow * K + k0 + kc);
    dst[0] = *(u16x8*)&tmp[0];
    dst[1] = *(u16x8*)&tmp[8];
}

__global__ __launch_bounds__(256)
void prep_kernel(const float* __restrict__ x, __hip_bfloat16* __restrict__ xm,
                 float* __restrict__ ld,
                 const float* __restrict__ W1, __hip_bfloat16* __restrict__ W1T,
                 const float* __restrict__ W2, __hip_bfloat16* __restrict__ W2T,
                 const float* __restrict__ W3, __hip_bfloat16* __restrict__ W3T)
{
    __shared__ unsigned short lds[64][66];
    const int bid = blockIdx.x;
    const int t   = threadIdx.x;

    if (bid < 4096) {
        if (t == 0) ld[bid] = 0.0f;
        const size_t r = bid;
        const float4* xp = (const float4*)(x + r * LFULL + (size_t)t * 16);
        float4 a = xp[0], b = xp[1], d = xp[2], e = xp[3];
        u16x8 v;
        v[0] = f2bf(a.x); v[1] = f2bf(a.z);
        v[2] = f2bf(b.x); v[3] = f2bf(b.z);
        v[4] = f2bf(d.x); v[5] = f2bf(d.z);
        v[6] = f2bf(e.x); v[7] = f2bf(e.z);
        *(u16x8*)(xm + r * NHALF + (size_t)t * 8) = v;
    } else if (bid < 5120) {
        int b = bid - 4096;
        transpose_body(W1, W1T, HDIM, HDIM, b & 31, b >> 5, false, lds, t);
    } else if (bid < 6144) {
        int b = bid - 5120;
        transpose_body(W2, W2T, HDIM, HDIM, b & 31, b >> 5, false, lds, t);
    } else {
        int b = bid - 6144;
        transpose_body(W3, W3T, HDIM, LFULL, b & 63, b >> 6, true, lds, t);
    }
}

// ---------------------------------------------------------------------------
// 8-phase GEMM, counted-wait pipelined, minimal barriers (2 per K-tile).
// FUSED (GEMM3): consecutive-j s/t pairing in-register (frag0/1=s, frag2/3=t
// via PERM), coalesced float4 x-read / y-write, log_det atomics.
// ---------------------------------------------------------------------------
template<int BM, int BN, int KD, int NOUT, bool RELU, bool FUSED>
__global__ __launch_bounds__(512)
void gemm8p(const __hip_bfloat16* __restrict__ A,
            const __hip_bfloat16* __restrict__ BT,
            const float* __restrict__ bias,
            __hip_bfloat16* __restrict__ C,
            const float* __restrict__ xg,
            float* __restrict__ yg,
            float* __restrict__ ldg)
{
    constexpr int MF = BM / 32, NF = BN / 64, MH = MF / 2, NH = NF / 2;
    constexpr int LA = BM / 128, LB = BN / 128;
    constexpr int NT = KD / 64;
    constexpr int ABYTES = BM * 128, BBYTES = BN * 128;
    constexpr int BBASE = 2 * ABYTES;
    __shared__ __align__(1024) char lds[2 * ABYTES + 2 * BBYTES];

    const int tid  = threadIdx.x;
    const int wave = tid >> 6, lane = tid & 63;
    const int wm = wave >> 2, wn = wave & 3;
    const int l15 = lane & 15, lhi = lane >> 4;

    // XCD-aware bijective swizzle (grid multiple of 8)
    const int nwg = gridDim.x;
    const int bid = blockIdx.x;
    const int wg  = (bid & 7) * (nwg >> 3) + (bid >> 3);
    constexpr int NBN = NOUT / BN;
    const int bm = wg / NBN, bn = wg % NBN;

    const __hip_bfloat16* gA = A  + (size_t)(bm * BM) * KD;
    const __hip_bfloat16* gB = BT + (size_t)(bn * BN) * KD;

    // staging: row=tid>>3, 16B chunk=tid&7; source chunk XOR-swizzled by row&7
    const int srow = tid >> 3;
    const int scol = ((tid & 7) ^ (srow & 7)) * 8;   // elements
    char* sd = lds + srow * 128 + (tid & 7) * 16;    // linear LDS dest

    const __hip_bfloat16* pA = gA + (size_t)srow * KD + scol;
    const __hip_bfloat16* pB = gB + (size_t)srow * KD + scol;

    // ---- prologue: B(0)->Bbuf0, A(0)->Abuf0, B(1)->Bbuf1
    #pragma unroll
    for (int s = 0; s < LB; ++s) gload_lds16(pB + (size_t)(s * 64) * KD,             sd + BBASE + s * 8192);
    #pragma unroll
    for (int s = 0; s < LB; ++s) gload_lds16(pB + (size_t)(BN/2 + s * 64) * KD,      sd + BBASE + (BN/2) * 128 + s * 8192);
    #pragma unroll
    for (int s = 0; s < LA; ++s) gload_lds16(pA + (size_t)(s * 64) * KD,             sd + s * 8192);
    #pragma unroll
    for (int s = 0; s < LA; ++s) gload_lds16(pA + (size_t)(BM/2 + s * 64) * KD,      sd + (BM/2) * 128 + s * 8192);
    #pragma unroll
    for (int s = 0; s < LB; ++s) gload_lds16(pB + 64 + (size_t)(s * 64) * KD,        sd + BBASE + BBYTES + s * 8192);
    #pragma unroll
    for (int s = 0; s < LB; ++s) gload_lds16(pB + 64 + (size_t)(BN/2 + s * 64) * KD, sd + BBASE + BBYTES + (BN/2) * 128 + s * 8192);
    pA += 64; pB += 128;
    asm volatile("s_waitcnt vmcnt(4)" ::: "memory");
    __builtin_amdgcn_s_barrier();

    // ---- invariant per-lane LDS read bases (swizzle folds to (l15&7)<<4)
    const int arow0 = wm * (BM / 2) + l15;
    const int brow0 = wn * (BN / 4) + l15;
    const int swz   = (l15 & 7) << 4;
    const int colX[2] = { (lhi * 16) ^ swz, (64 + lhi * 16) ^ swz };
    const char* rA = lds + arow0 * 128;
    const char* rB = lds + brow0 * 128;

    bf16x8 af[MH][2], bf0[NH][2], bf1[NH][2];
    f32x4 acc[MF][NF] = {};

    // pre-read aLO(0), bLO(0)
    #pragma unroll
    for (int m = 0; m < MH; ++m)
        #pragma unroll
        for (int kk = 0; kk < 2; ++kk)
            af[m][kk] = *(const bf16x8*)(rA + colX[kk] + m * 2048);
    #pragma unroll
    for (int n = 0; n < NH; ++n)
        #pragma unroll
        for (int kk = 0; kk < 2; ++kk)
            bf0[n][kk] = *(const bf16x8*)(rB + colX[kk] + (BBASE + n * 2048));

    auto body = [&](int t, auto bufc) {
        constexpr int BUF   = decltype(bufc)::value;
        constexpr int ABUF  = BUF * ABYTES;
        constexpr int ABUFo = (BUF ^ 1) * ABYTES;
        constexpr int BBUF  = BBASE + BUF * BBYTES;
        constexpr int BBUFo = BBASE + (BUF ^ 1) * BBYTES;

        // ---- P0: stage A0(t+1); MFMA q00; read bHI(t)   [no barrier]
        if (t + 1 < NT) {
            #pragma unroll
            for (int s = 0; s < LA; ++s)
                gload_lds16(pA + (size_t)(s * 64) * KD, sd + ABUFo + s * 8192);
        }
        __builtin_amdgcn_s_setprio(1);
        #pragma unroll
        for (int kk = 0; kk < 2; ++kk)
            #pragma unroll
            for (int m = 0; m < MH; ++m)
                #pragma unroll
                for (int n = 0; n < NH; ++n)
                    acc[m][n] = __builtin_amdgcn_mfma_f32_16x16x32_bf16(af[m][kk], bf0[n][kk], acc[m][n], 0, 0, 0);
        __builtin_amdgcn_s_setprio(0);
        #pragma unroll
        for (int n = 0; n < NH; ++n)
            #pragma unroll
            for (int kk = 0; kk < 2; ++kk)
                bf1[n][kk] = *(const bf16x8*)(rB + colX[kk] + (BBUF + (NH + n) * 2048));

        // ---- P1: stage A1(t+1); MFMA q01; read aHI(t); BARRIER
        if (t + 1 < NT) {
            #pragma unroll
            for (int s = 0; s < LA; ++s)
                gload_lds16(pA + (size_t)(BM/2 + s * 64) * KD, sd + ABUFo + (BM/2) * 128 + s * 8192);
        }
        __builtin_amdgcn_s_setprio(1);
        #pragma unroll
        for (int kk = 0; kk < 2; ++kk)
            #pragma unroll
            for (int m = 0; m < MH; ++m)
                #pragma unroll
                for (int n = 0; n < NH; ++n)
                    acc[m][NH + n] = __builtin_amdgcn_mfma_f32_16x16x32_bf16(af[m][kk], bf1[n][kk], acc[m][NH + n], 0, 0, 0);
        __builtin_amdgcn_s_setprio(0);
        #pragma unroll
        for (int m = 0; m < MH; ++m)
            #pragma unroll
            for (int kk = 0; kk < 2; ++kk)
                af[m][kk] = *(const bf16x8*)(rA + colX[kk] + (ABUF + (MH + m) * 2048));
        __builtin_amdgcn_s_barrier();

        // ---- P2: stage B0(t+2); MFMA q10   [no barrier]
        if (t + 2 < NT) {
            #pragma unroll
            for (int s = 0; s < LB; ++s)
                gload_lds16(pB + (size_t)(s * 64) * KD, sd + BBUF + s * 8192);
        }
        __builtin_amdgcn_s_setprio(1);
        #pragma unroll
        for (int kk = 0; kk < 2; ++kk)
            #pragma unroll
            for (int m = 0; m < MH; ++m)
                #pragma unroll
                for (int n = 0; n < NH; ++n)
                    acc[MH + m][n] = __builtin_amdgcn_mfma_f32_16x16x32_bf16(af[m][kk], bf0[n][kk], acc[MH + m][n], 0, 0, 0);
        __builtin_amdgcn_s_setprio(0);

        // ---- P3: stage B1(t+2); vmcnt; BARRIER;
        //          read bLO(t+1); MFMA q11; read aLO(t+1)
        if (t + 2 < NT) {
            #pragma unroll
            for (int s = 0; s < LB; ++s)
                gload_lds16(pB + (size_t)(BN/2 + s * 64) * KD, sd + BBUF + (BN/2) * 128 + s * 8192);
            asm volatile("s_waitcnt vmcnt(4)" ::: "memory");
        } else {
            asm volatile("s_waitcnt vmcnt(0)" ::: "memory");
        }
        __builtin_amdgcn_s_barrier();
        if (t + 1 < NT) {
            #pragma unroll
            for (int n = 0; n < NH; ++n)
                #pragma unroll
                for (int kk = 0; kk < 2; ++kk)
                    bf0[n][kk] = *(const bf16x8*)(rB + colX[kk] + (BBUFo + n * 2048));
        }
        __builtin_amdgcn_s_setprio(1);
        #pragma unroll
        for (int kk = 0; kk < 2; ++kk)
            #pragma unroll
            for (int m = 0; m < MH; ++m)
                #pragma unroll
                for (int n = 0; n < NH; ++n)
                    acc[MH + m][NH + n] = __builtin_amdgcn_mfma_f32_16x16x32_bf16(af[m][kk], bf1[n][kk], acc[MH + m][NH + n], 0, 0, 0);
        __builtin_amdgcn_s_setprio(0);
        if (t + 1 < NT) {
            #pragma unroll
            for (int m = 0; m < MH; ++m)
                #pragma unroll
                for (int kk = 0; kk < 2; ++kk)
                    af[m][kk] = *(const bf16x8*)(rA + colX[kk] + (ABUFo + m * 2048));
        }
        pA += 64; pB += 64;
    };

    for (int tt = 0; tt < NT; tt += 2) {
        body(tt,     ICt<0>{});
        body(tt + 1, ICt<1>{});
    }

    const int crow0 = bm * BM + wm * (BM / 2) + lhi * 4;
    if constexpr (FUSED) {
        // PERM pairing: frag0=s_{j0}, frag1=s_{j0+1}, frag2=t_{j0},
        // frag3=t_{j0+1}, j0 = bn*128 + wn*32 + 2*l15 (even).
        // x/y access: one float4 at col 2*j0 (coalesced across l15).
        const int j0 = bn * (BN / 2) + wn * 32 + 2 * l15;
        const float2 sbv = *(const float2*)(bias + j0);
        const float2 tbv = *(const float2*)(bias + NHALF + j0);
        #pragma unroll
        for (int m = 0; m < MF; ++m) {
            #pragma unroll
            for (int r = 0; r < 4; ++r) {
                const int row = crow0 + m * 16 + r;
                float s0 = acc[m][0][r] + sbv.x;
                float s1 = acc[m][1][r] + sbv.y;
                float t0 = acc[m][2][r] + tbv.x;
                float t1 = acc[m][3][r] + tbv.y;
                float a0 = 2.0f * fast_tanh(s0);
                float a1 = 2.0f * fast_tanh(s1);
                float4 xv = *(const float4*)(xg + (size_t)row * LFULL + 2 * j0);
                float4 yv;
                yv.x = xv.x;                       // even col: exact copy
                yv.y = xv.y * __expf(a0) + t0;     // odd col: affine update
                yv.z = xv.z;
                yv.w = xv.w * __expf(a1) + t1;
                *(float4*)(yg + (size_t)row * LFULL + 2 * j0) = yv;
                float ldp = a0 + a1;
                ldp += __shfl_xor(ldp, 1, 64);
                ldp += __shfl_xor(ldp, 2, 64);
                ldp += __shfl_xor(ldp, 4, 64);
                ldp += __shfl_xor(ldp, 8, 64);
                if (l15 == 0) atomicAdd(&ldg[row], ldp);
            }
        }
    } else {
        // ---- C write: col = lane&15 (+n*16), row = lhi*4 + r (+m*16)
        const int ccol0 = bn * BN + wn * (BN / 4) + l15;
        #pragma unroll
        for (int m = 0; m < MF; ++m) {
            #pragma unroll
            for (int n = 0; n < NF; ++n) {
                int col = ccol0 + n * 16;
                float bv = bias[col];
                #pragma unroll
                for (int r = 0; r < 4; ++r) {
                    int row = crow0 + m * 16 + r;
                    float v = acc[m][n][r] + bv;
                    if (RELU) v = (v > 0.0f) ? v : 0.2f * v;
                    C[(size_t)row * NOUT + col] = __float2bfloat16(v);
                }
            }
        }
    }
}

// ---------------------------------------------------------------------------
extern "C" void kernel_launch(void* const* d_in, const int* in_sizes, int n_in,
                              void* d_out, int out_size, void* d_ws, size_t ws_size,
                              hipStream_t stream)
{
    const float* x  = (const float*)d_in[0];
    const float* W1 = (const float*)d_in[1];
    const float* b1 = (const float*)d_in[2];
    const float* W2 = (const float*)d_in[3];
    const float* b2 = (const float*)d_in[4];
    const float* W3 = (const float*)d_in[5];
    const float* b3 = (const float*)d_in[6];

    char* ws = (char*)d_ws;
    const size_t MB = 1u << 20;
    __hip_bfloat16* W3T  = (__hip_bfloat16*)(ws);              // 16 MB: 4096x2048 (PERM)
    __hip_bfloat16* h2   = (__hip_bfloat16*)(ws + 16 * MB);    // 16 MB: 4096x2048
    __hip_bfloat16* xmb  = (__hip_bfloat16*)(ws + 32 * MB);    // 16 MB
    __hip_bfloat16* W1T  = (__hip_bfloat16*)(ws + 48 * MB);    //  8 MB
    __hip_bfloat16* W2T  = (__hip_bfloat16*)(ws + 56 * MB);    //  8 MB
    __hip_bfloat16* h1   = (__hip_bfloat16*)(ws + 64 * MB);    // 16 MB

    float* y  = (float*)d_out;
    float* ld = y + (size_t)MROWS * LFULL;

    prep_kernel<<<8192, 256, 0, stream>>>(x, xmb, ld, W1, W1T, W2, W2T, W3, W3T);

    gemm8p<128, 256, 2048, 2048, true,  false><<<dim3(256), dim3(512), 0, stream>>>(xmb, W1T, b1, h1, nullptr, nullptr, nullptr);
    gemm8p<128, 256, 2048, 2048, true,  false><<<dim3(256), dim3(512), 0, stream>>>(h1,  W2T, b2, h2, nullptr, nullptr, nullptr);
    gemm8p<256, 256, 2048, 4096, false, true ><<<dim3(256), dim3(512), 0, stream>>>(h2,  W3T, b3, nullptr, x, y, ld);
}